// Round 11
// baseline (215.055 us; speedup 1.0000x reference)
//
#include <hip/hip_runtime.h>
#include <hip/hip_bf16.h>

// R15: R14's wave-autonomous single-pass structure + numerics fixes.
// R14 failed (indices absmax 512): (1) f16-RTZ retention error is 1 ulp
// one-sided = 4.9e-4 at |s|~0.5-1 (score magnitudes reach ~0.9), so the band
// condition  stored(c*) - stored_min <= EPS  had ZERO margin at EPS=1e-3;
// (2) hard per-wave queue cap 256 could drop candidates on bursts.
// Fixes: RNE f16 pack (half-ulp symmetric 2.44e-4 at |s|~0.5), EPS=2e-3
// (error chain 5e-4 MFMA + 2x2.44e-4 storage ~ 1e-3 -> 2x margin; even at
// |s|=2: 1.5e-3 < 2e-3), QW=512/wave (2x the validated shared capacity).
// Exact fp32 reference rescore + u64 (dist<<32|idx) atomicMin strict-<
// ascending-k tie-break unchanged -> final indices/outputs bit-identical to
// reference whenever the true argmin is in the band (2x-margined).
// Structure (from R14, motivated by R6-R13 invariance evidence): wave owns
// rows [16w,16w+16) end-to-end; single dense MFMA pass, f16-packed scores in
// 32 VGPRs; no block barriers in the tile loop; persistent 512 blocks x 4
// tiles; unroll = 4 static chunks of 8 + sched_barrier(0) (R10/R11 lesson);
// waves_per_eu(2,2) -> 256-reg budget, no spill (R7/R8 lesson).
constexpr int NELEM = 8388608;            // 32*64*64*64
constexpr int ROWS  = 64;                 // rows per tile
constexpr int TPB   = 4;                  // tiles per block
constexpr int NBLK  = 131072 / ROWS / TPB;  // 512 blocks = 2/CU, all resident
constexpr int ZS    = 68;                 // fp32 z tile stride (dwords)
constexpr float EPS = 2e-3f;              // band (2x margin vs f16-rne chain)
constexpr int QW    = 512;                // per-wave candidate cap (~50 expected)

typedef short bf16x8 __attribute__((ext_vector_type(8)));
typedef float v4f    __attribute__((ext_vector_type(4)));

// Precomputed E fragments, hi-only, scale -2: [ct][kc][lane] -> 8 bf16, 64 KB.
__device__ bf16x8 g_efrag[32][2][64];
// Precomputed ||e||^2 in exact reference quad-accumulator order.
__device__ float  g_en2[512];

__device__ inline bf16x8 cvt_hi8(const float* __restrict__ s, float scale) {
    bf16x8 h;
#pragma unroll
    for (int j = 0; j < 8; ++j) {
        __hip_bfloat16 b = __float2bfloat16(scale * s[j]);
        h[j] = (short)__bfloat16_as_ushort(b);
    }
    return h;
}

__device__ inline unsigned pkrne2(float a, float b) {   // f16 pack, RNE
    union { _Float16 h; unsigned short s; } ca, cb;
    ca.h = (_Float16)a;                  // v_cvt_f16_f32 (round-nearest-even)
    cb.h = (_Float16)b;
    return (unsigned)ca.s | ((unsigned)cb.s << 16);
}
__device__ inline unsigned pkmin2(unsigned a, unsigned b) {  // packed f16 min
    unsigned d; asm("v_pk_min_f16 %0, %1, %2" : "=v"(d) : "v"(a), "v"(b));
    return d;
}
__device__ inline float h2lo(unsigned u) {
    union { unsigned short s; _Float16 h; } c; c.s = (unsigned short)(u & 0xffffu);
    return (float)c.h;
}
__device__ inline float h2hi(unsigned u) {
    union { unsigned short s; _Float16 h; } c; c.s = (unsigned short)(u >> 16);
    return (float)c.h;
}

// 17 blocks: 0..15 build E fragments (256 entries each), 16 builds en2 + out[0]=0.
__global__ void __launch_bounds__(256) vq_prep(const float* __restrict__ emb,
                                               float* __restrict__ out) {
    const int b = blockIdx.x;
    if (b < 16) {
        const int id   = b * 256 + threadIdx.x;   // (ct,kc,lane), 4096 total
        const int lane = id & 63;
        const int kc   = (id >> 6) & 1;
        const int ct   = id >> 7;
        const float* src = emb + (size_t)(ct * 16 + (lane & 15)) * 64
                               + kc * 32 + (lane >> 4) * 8;
        g_efrag[ct][kc][lane] = cvt_hi8(src, -2.0f);
    } else {
#pragma unroll
        for (int c = 0; c < 2; ++c) {
            const int k = threadIdx.x + c * 256;
            const float4* e4 = (const float4*)(emb + (size_t)k * 64);
            float a = 0.f, bq = 0.f, cc = 0.f, d = 0.f;
#pragma unroll
            for (int i = 0; i < 16; ++i) {
                float4 v = e4[i];
                a += v.x * v.x; bq += v.y * v.y; cc += v.z * v.z; d += v.w * v.w;
            }
            g_en2[k] = (a + bq) + (cc + d);
        }
        if (threadIdx.x == 0) out[0] = 0.f;
    }
}

// Block = 256 threads = 4 autonomous waves. Wave w owns rows [16w,16w+16) of
// each tile: stages its own z rows, computes zn2/zf, one dense MFMA pass over
// all 512 codes with f16-packed score retention, wave-local band scan into a
// per-wave queue, wave-local exact rescore + atomicMin, wave-local epilogue.
// MFMA 16x16x32: A=-2E (m=code), B=Z (n=row), C: col=lane&15 (row),
// row-of-C=quad*4+reg (code) [m89 layout, R5-validated].
__global__ __launch_bounds__(256) __attribute__((amdgpu_waves_per_eu(2, 2)))
void vq_main(const float* __restrict__ z,
             const float* __restrict__ emb,
             float* __restrict__ out) {
    __shared__ float s_z[ROWS * ZS];          // 17.4 KB, wave w: rows 16w..16w+15
    __shared__ float s_en2[512];
    __shared__ float s_zn2[ROWS];
    __shared__ unsigned long long s_key[ROWS];
    __shared__ unsigned s_qw[4 * QW];         // per-wave queues (8 KB)
    __shared__ int s_qnw[4];
    __shared__ float s_lpart[4];

    const int tid  = threadIdx.x;
    const int lane = tid & 63;
    const int wid  = __builtin_amdgcn_readfirstlane(tid >> 6);
    const int mcol = lane & 15;
    const int quad = lane >> 4;
    const int rl4  = lane >> 2, seg = lane & 3;     // stage/zn2/epilogue map
    const int myrow = wid * 16 + rl4;               // block-local row
    const int zrow  = wid * 16 + mcol;              // this lane's MFMA row

    // ---- once: en2 cooperative stage (only block-wide dependency) ----
    s_en2[tid]       = g_en2[tid];
    s_en2[tid + 256] = g_en2[tid + 256];
    if (lane < 16) s_key[wid * 16 + lane] = ~0ULL;
    if (lane == 0) s_qnw[wid] = 0;
    __syncthreads();

    float lacc = 0.f;                                // lane0: loss across tiles

    for (int t = 0; t < TPB; ++t) {
        const size_t tb = (size_t)(blockIdx.x * TPB + t) * ROWS;

        // ---- stage this wave's 16 z rows (wave-private, no barrier) ----
        {
            const float4* gp = (const float4*)(z + (tb + myrow) * 64 + seg * 16);
            float4 v0 = gp[0], v1 = gp[1], v2 = gp[2], v3 = gp[3];
            float* d = &s_z[myrow * ZS + seg * 16];
            *(float4*)&d[0] = v0;  *(float4*)&d[4]  = v1;
            *(float4*)&d[8] = v2;  *(float4*)&d[12] = v3;
        }

        // ---- exact zn2 (reference quad-accumulator order, same grouping) ----
        {
            const float* zr = &s_z[myrow * ZS];
            float p = 0.f;
#pragma unroll
            for (int i = 0; i < 16; ++i) p += zr[4 * i + seg] * zr[4 * i + seg];
            p += __shfl_xor(p, 1, 64);   // a+b | c+d
            p += __shfl_xor(p, 2, 64);   // (a+b)+(c+d)
            if (seg == 0) s_zn2[myrow] = p;
        }

        // ---- Z fragments: 8 VGPRs, computed once ----
        const bf16x8 zf0 = cvt_hi8(&s_z[zrow * ZS +  0 + quad * 8], 1.0f);
        const bf16x8 zf1 = cvt_hi8(&s_z[zrow * ZS + 32 + quad * 8], 1.0f);

        // ---- single dense pass, f16-packed retention + running packed min ----
        unsigned sc0[16], sc1[16], sc2[16], sc3[16];
        unsigned mh = 0x7c007c00u;               // +inf | +inf

        auto dense8 = [&](int base, unsigned (&sc)[16]) {
#pragma unroll
            for (int c = 0; c < 8; ++c) {
                const int ct = base + c;
                bf16x8 e0 = g_efrag[ct][0][lane];
                bf16x8 e1 = g_efrag[ct][1][lane];
                v4f a = *(const v4f*)&s_en2[ct * 16 + quad * 4];
                a = __builtin_amdgcn_mfma_f32_16x16x32_bf16(e0, zf0, a, 0, 0, 0);
                a = __builtin_amdgcn_mfma_f32_16x16x32_bf16(e1, zf1, a, 0, 0, 0);
                unsigned p0 = pkrne2(a.x, a.y);
                unsigned p1 = pkrne2(a.z, a.w);
                sc[2 * c]     = p0;
                sc[2 * c + 1] = p1;
                mh = pkmin2(mh, pkmin2(p0, p1));
            }
        };
        dense8(0,  sc0); __builtin_amdgcn_sched_barrier(0);
        dense8(8,  sc1); __builtin_amdgcn_sched_barrier(0);
        dense8(16, sc2); __builtin_amdgcn_sched_barrier(0);
        dense8(24, sc3);

        // ---- row threshold (in-register; quads exchange via shfl) ----
        float fmn = fminf(h2lo(mh), h2hi(mh));
        fmn = fminf(fmn, __shfl_xor(fmn, 16, 64));
        fmn = fminf(fmn, __shfl_xor(fmn, 32, 64));
        const float thr = fmn + EPS;

        // ---- band scan over retained scores -> per-wave queue ----
        auto push = [&](int code) {
            int slot = atomicAdd(&s_qnw[wid], 1);
            if (slot < QW)
                s_qw[wid * QW + slot] = ((unsigned)zrow << 16) | (unsigned)code;
        };
        auto scan8 = [&](int base, const unsigned (&sc)[16]) {
#pragma unroll
            for (int c = 0; c < 8; ++c) {
                unsigned pm = pkmin2(sc[2 * c], sc[2 * c + 1]);
                if (fminf(h2lo(pm), h2hi(pm)) <= thr) {
                    const int code0 = (base + c) * 16 + quad * 4;
                    if (h2lo(sc[2 * c])     <= thr) push(code0 + 0);
                    if (h2hi(sc[2 * c])     <= thr) push(code0 + 1);
                    if (h2lo(sc[2 * c + 1]) <= thr) push(code0 + 2);
                    if (h2hi(sc[2 * c + 1]) <= thr) push(code0 + 3);
                }
            }
        };
        scan8(0, sc0); scan8(8, sc1); scan8(16, sc2); scan8(24, sc3);

        // ---- wave-local exact reference rescore (no barrier) ----
        {
            const int qn = s_qnw[wid];
            for (int i = lane; i < qn && i < QW; i += 64) {
                const unsigned e = s_qw[wid * QW + i];
                const int row = e >> 16, code = e & 0xFFFF;
                const float* zr = &s_z[row * ZS];
                const float* er = emb + (size_t)code * 64;
                float a = 0.f, b = 0.f, c2 = 0.f, d = 0.f;
#pragma unroll
                for (int g = 0; g < 16; ++g) {
                    a  += zr[4*g]   * er[4*g];   b += zr[4*g+1] * er[4*g+1];
                    c2 += zr[4*g+2] * er[4*g+2]; d += zr[4*g+3] * er[4*g+3];
                }
                float dot  = (a + b) + (c2 + d);
                float dist = (s_zn2[row] + s_en2[code]) - 2.0f * dot;  // ref expr
                unsigned long long key =
                    ((unsigned long long)__float_as_uint(dist) << 32) | (unsigned)code;
                atomicMin(&s_key[row], key);
            }
        }

        // ---- wave-local epilogue: quantized_st, indices, loss ----
        {
            const int widx = (int)(unsigned)(s_key[myrow] & 0x1FFULL);
            const float* er = emb + (size_t)widx * 64 + seg * 16;
            const float* zr = &s_z[myrow * ZS + seg * 16];
            float* qo = out + 1 + (tb + myrow) * 64 + seg * 16;
            float lsum = 0.f;
#pragma unroll
            for (int j = 0; j < 16; ++j) {
                float zv = zr[j], ev = er[j];
                float q = zv + (ev - zv);    // reference STE arithmetic
                float df = q - zv; lsum += df * df;
                qo[j] = q;
            }
            if (seg == 0)
                out[1 + NELEM + tb + myrow] = (float)widx;
#pragma unroll
            for (int off = 32; off; off >>= 1) lsum += __shfl_down(lsum, off, 64);
            if (lane == 0) lacc += lsum;     // per-tile reduction order preserved
        }

        // ---- wave-local turnover (after all uses, before next tile) ----
        if (lane < 16) s_key[wid * 16 + lane] = ~0ULL;
        if (lane == 0) s_qnw[wid] = 0;
    }

    // ---- one final block reduction for the loss ----
    if (lane == 0) s_lpart[wid] = lacc;
    __syncthreads();
    if (tid == 0) {
        float p = (s_lpart[0] + s_lpart[1]) + (s_lpart[2] + s_lpart[3]);
        atomicAdd(out, p * (1.25f / 8388608.0f));   // recon + 0.25*commit
    }
}

extern "C" void kernel_launch(void* const* d_in, const int* in_sizes, int n_in,
                              void* d_out, int out_size, void* d_ws, size_t ws_size,
                              hipStream_t stream) {
    const float* z   = (const float*)d_in[0];
    const float* emb = (const float*)d_in[1];
    float* out = (float*)d_out;

    vq_prep<<<17, 256, 0, stream>>>(emb, out);   // also zeroes out[0]
    vq_main<<<NBLK, 256, 0, stream>>>(z, emb, out);
}

// Round 12
// 150.708 us; speedup vs baseline: 1.4270x; 1.4270x over previous
//
#include <hip/hip_runtime.h>
#include <hip/hip_bf16.h>

// R16: wave-autonomous TWO-PASS RECOMPUTE (no retention, no spill) —
// the barrier-free experiment R14/R15 was meant to be, minus their fatal
// register demand. R15 lesson (3rd confirmation): any structure needing
// >~110 live arch VGPRs spills on this compiler regardless of waves_per_eu;
// retention (64 regs) + unrolled load batches cannot fit. Recompute can:
// R11's unroll-4 two-pass compiled to 52 VGPRs spill-free.
// Structure: wave w owns rows [16w,16w+16) end-to-end (stage, zn2, zf,
// pass1 min -> thr in-register via shfl, pass2 recompute + band scan into a
// PER-WAVE queue, wave-local exact rescore + atomicMin, wave-local epilogue,
// wave-local resets). ZERO barriers in the tile loop; one barrier at block
// start (shared s_en2). Persistent 512 blocks x 4 tiles, register z-prefetch
// (R13 pattern, now barrier-free). This isolates the block-lockstep convoy:
// six prior structures all kept phase barriers and all landed 61-64 us.
// Numerics identical to R6/R11/R12/R13 (absmax 0.0): single-product bf16
// scores (emb ~ U(+-1/512)), EPS=1e-3 band, exact fp32 reference rescore
// (same accumulator grouping), u64 (dist_bits<<32|idx) atomicMin strict-<
// ascending-k tie-break. Pass1/pass2 use identical zf/e/base bits -> mins
// match exactly. Per-wave queue cap 512 ~ 18x expected (~28/wave).
constexpr int NELEM = 8388608;            // 32*64*64*64
constexpr int ROWS  = 64;                 // rows per tile
constexpr int TPB   = 4;                  // tiles per block
constexpr int NBLK  = 131072 / ROWS / TPB;  // 512 blocks = 2/CU, all resident
constexpr int ZS    = 68;                 // fp32 z tile stride (dwords)
constexpr float EPS = 1e-3f;              // band (R6-validated)
constexpr int QW    = 512;                // per-wave candidate cap

typedef short bf16x8 __attribute__((ext_vector_type(8)));
typedef float v4f    __attribute__((ext_vector_type(4)));

// Precomputed E fragments, hi-only, scale -2: [ct][kc][lane] -> 8 bf16, 64 KB.
__device__ bf16x8 g_efrag[32][2][64];
// Precomputed ||e||^2 in exact reference quad-accumulator order.
__device__ float  g_en2[512];

__device__ inline bf16x8 cvt_hi8(const float* __restrict__ s, float scale) {
    bf16x8 h;
#pragma unroll
    for (int j = 0; j < 8; ++j) {
        __hip_bfloat16 b = __float2bfloat16(scale * s[j]);
        h[j] = (short)__bfloat16_as_ushort(b);
    }
    return h;
}

// 17 blocks: 0..15 build E fragments (256 entries each), 16 builds en2 + out[0]=0.
__global__ void __launch_bounds__(256) vq_prep(const float* __restrict__ emb,
                                               float* __restrict__ out) {
    const int b = blockIdx.x;
    if (b < 16) {
        const int id   = b * 256 + threadIdx.x;   // (ct,kc,lane), 4096 total
        const int lane = id & 63;
        const int kc   = (id >> 6) & 1;
        const int ct   = id >> 7;
        const float* src = emb + (size_t)(ct * 16 + (lane & 15)) * 64
                               + kc * 32 + (lane >> 4) * 8;
        g_efrag[ct][kc][lane] = cvt_hi8(src, -2.0f);
    } else {
#pragma unroll
        for (int c = 0; c < 2; ++c) {
            const int k = threadIdx.x + c * 256;
            const float4* e4 = (const float4*)(emb + (size_t)k * 64);
            float a = 0.f, bq = 0.f, cc = 0.f, d = 0.f;
#pragma unroll
            for (int i = 0; i < 16; ++i) {
                float4 v = e4[i];
                a += v.x * v.x; bq += v.y * v.y; cc += v.z * v.z; d += v.w * v.w;
            }
            g_en2[k] = (a + bq) + (cc + d);
        }
        if (threadIdx.x == 0) out[0] = 0.f;
    }
}

// Block = 256 threads = 4 autonomous waves. MFMA 16x16x32: A=-2E (m=code),
// B=Z (n=row), C: col=lane&15 (row), row-of-C=quad*4+reg (code)
// [m89 layout, R5-validated].
__global__ __launch_bounds__(256) __attribute__((amdgpu_waves_per_eu(2, 2)))
void vq_main(const float* __restrict__ z,
             const float* __restrict__ emb,
             float* __restrict__ out) {
    __shared__ float s_z[ROWS * ZS];          // 17.4 KB, wave w: rows 16w..16w+15
    __shared__ float s_en2[512];
    __shared__ float s_zn2[ROWS];
    __shared__ unsigned long long s_key[ROWS];
    __shared__ unsigned s_qw[4 * QW];         // per-wave queues (8 KB)
    __shared__ int s_qnw[4];
    __shared__ float s_lpart[4];

    const int tid  = threadIdx.x;
    const int lane = tid & 63;
    const int wid  = __builtin_amdgcn_readfirstlane(tid >> 6);
    const int mcol = lane & 15;
    const int quad = lane >> 4;
    const int rl4  = lane >> 2, seg = lane & 3;     // stage/zn2/epilogue map
    const int myrow = wid * 16 + rl4;               // block-local row
    const int zrow  = wid * 16 + mcol;              // this lane's MFMA row

    // ---- once: en2 cooperative stage (the ONLY block-wide dependency) ----
    s_en2[tid]       = g_en2[tid];
    s_en2[tid + 256] = g_en2[tid + 256];
    if (lane < 16) s_key[wid * 16 + lane] = ~0ULL;
    if (lane == 0) s_qnw[wid] = 0;
    // stage tile 0's z rows (wave-private)
    {
        const float4* gp = (const float4*)(z +
            ((size_t)blockIdx.x * TPB * ROWS + myrow) * 64 + seg * 16);
        float4 v0 = gp[0], v1 = gp[1], v2 = gp[2], v3 = gp[3];
        float* d = &s_z[myrow * ZS + seg * 16];
        *(float4*)&d[0] = v0;  *(float4*)&d[4]  = v1;
        *(float4*)&d[8] = v2;  *(float4*)&d[12] = v3;
    }
    __syncthreads();                                // covers s_en2 only

    float lacc = 0.f;                               // lane0: loss across tiles

    for (int t = 0; t < TPB; ++t) {
        const size_t tb = (size_t)(blockIdx.x * TPB + t) * ROWS;

        // ---- prefetch next tile's z into 16 VGPRs (hidden under this tile) ----
        float4 pf0, pf1, pf2, pf3;
        if (t + 1 < TPB) {
            const float4* gp = (const float4*)(z + (tb + ROWS + myrow) * 64 + seg * 16);
            pf0 = gp[0]; pf1 = gp[1]; pf2 = gp[2]; pf3 = gp[3];
        }

        // ---- exact zn2 (reference quad-accumulator order), wave-local ----
        {
            const float* zr = &s_z[myrow * ZS];
            float p = 0.f;
#pragma unroll
            for (int i = 0; i < 16; ++i) p += zr[4 * i + seg] * zr[4 * i + seg];
            p += __shfl_xor(p, 1, 64);   // a+b | c+d
            p += __shfl_xor(p, 2, 64);   // (a+b)+(c+d)
            if (seg == 0) s_zn2[myrow] = p;
        }

        // ---- Z fragments: 8 VGPRs, computed once per tile ----
        const bf16x8 zf0 = cvt_hi8(&s_z[zrow * ZS +  0 + quad * 8], 1.0f);
        const bf16x8 zf1 = cvt_hi8(&s_z[zrow * ZS + 32 + quad * 8], 1.0f);

        // ---- pass 1: row min over all 512 codes (unroll 4, R11-proven) ----
        float lmin = 3.402823466e38f;
#pragma unroll 4
        for (int ct = 0; ct < 32; ++ct) {
            bf16x8 e0 = g_efrag[ct][0][lane];
            bf16x8 e1 = g_efrag[ct][1][lane];
            v4f a = *(const v4f*)&s_en2[ct * 16 + quad * 4];  // broadcast read
            a = __builtin_amdgcn_mfma_f32_16x16x32_bf16(e0, zf0, a, 0, 0, 0);
            a = __builtin_amdgcn_mfma_f32_16x16x32_bf16(e1, zf1, a, 0, 0, 0);
            lmin = fminf(lmin, fminf(fminf(a.x, a.y), fminf(a.z, a.w)));
        }
        lmin = fminf(lmin, __shfl_xor(lmin, 16, 64));
        lmin = fminf(lmin, __shfl_xor(lmin, 32, 64));
        const float thr = lmin + EPS;     // in-register; no barrier

        // ---- pass 2: recompute (identical bits), band scan -> wave queue ----
#pragma unroll 4
        for (int ct = 0; ct < 32; ++ct) {
            bf16x8 e0 = g_efrag[ct][0][lane];
            bf16x8 e1 = g_efrag[ct][1][lane];
            v4f a = *(const v4f*)&s_en2[ct * 16 + quad * 4];
            a = __builtin_amdgcn_mfma_f32_16x16x32_bf16(e0, zf0, a, 0, 0, 0);
            a = __builtin_amdgcn_mfma_f32_16x16x32_bf16(e1, zf1, a, 0, 0, 0);
            float m4 = fminf(fminf(a.x, a.y), fminf(a.z, a.w));
            if (m4 <= thr) {
#pragma unroll
                for (int r = 0; r < 4; ++r) {
                    if (a[r] <= thr) {
                        int slot = atomicAdd(&s_qnw[wid], 1);
                        if (slot < QW)
                            s_qw[wid * QW + slot] =
                                ((unsigned)zrow << 16) |
                                (unsigned)(ct * 16 + quad * 4 + r);
                    }
                }
            }
        }

        // ---- wave-local exact reference rescore (no barrier) ----
        {
            const int qn = s_qnw[wid];
            for (int i = lane; i < qn && i < QW; i += 64) {
                const unsigned e = s_qw[wid * QW + i];
                const int row = e >> 16, code = e & 0xFFFF;
                const float* zr = &s_z[row * ZS];
                const float* er = emb + (size_t)code * 64;
                float a = 0.f, b = 0.f, c2 = 0.f, d = 0.f;
#pragma unroll
                for (int g = 0; g < 16; ++g) {
                    a  += zr[4*g]   * er[4*g];   b += zr[4*g+1] * er[4*g+1];
                    c2 += zr[4*g+2] * er[4*g+2]; d += zr[4*g+3] * er[4*g+3];
                }
                float dot  = (a + b) + (c2 + d);
                float dist = (s_zn2[row] + s_en2[code]) - 2.0f * dot;  // ref expr
                unsigned long long key =
                    ((unsigned long long)__float_as_uint(dist) << 32) | (unsigned)code;
                atomicMin(&s_key[row], key);
            }
        }

        // ---- wave-local epilogue: quantized_st, indices, loss ----
        {
            const int widx = (int)(unsigned)(s_key[myrow] & 0x1FFULL);
            const float* er = emb + (size_t)widx * 64 + seg * 16;
            const float* zr = &s_z[myrow * ZS + seg * 16];
            float* qo = out + 1 + (tb + myrow) * 64 + seg * 16;
            float lsum = 0.f;
#pragma unroll
            for (int j = 0; j < 16; ++j) {
                float zv = zr[j], ev = er[j];
                float q = zv + (ev - zv);    // reference STE arithmetic
                float df = q - zv; lsum += df * df;
                qo[j] = q;
            }
            if (seg == 0)
                out[1 + NELEM + tb + myrow] = (float)widx;
#pragma unroll
            for (int off = 32; off; off >>= 1) lsum += __shfl_down(lsum, off, 64);
            if (lane == 0) lacc += lsum;
        }

        // ---- wave-local turnover: resets + stage next tile from regs ----
        if (lane < 16) s_key[wid * 16 + lane] = ~0ULL;
        if (lane == 0) s_qnw[wid] = 0;
        if (t + 1 < TPB) {
            float* d = &s_z[myrow * ZS + seg * 16];
            *(float4*)&d[0]  = pf0;  *(float4*)&d[4]  = pf1;
            *(float4*)&d[8]  = pf2;  *(float4*)&d[12] = pf3;
        }
    }

    // ---- one final block reduction for the loss ----
    if (lane == 0) s_lpart[wid] = lacc;
    __syncthreads();
    if (tid == 0) {
        float p = (s_lpart[0] + s_lpart[1]) + (s_lpart[2] + s_lpart[3]);
        atomicAdd(out, p * (1.25f / 8388608.0f));   // recon + 0.25*commit
    }
}

extern "C" void kernel_launch(void* const* d_in, const int* in_sizes, int n_in,
                              void* d_out, int out_size, void* d_ws, size_t ws_size,
                              hipStream_t stream) {
    const float* z   = (const float*)d_in[0];
    const float* emb = (const float*)d_in[1];
    float* out = (float*)d_out;

    vq_prep<<<17, 256, 0, stream>>>(emb, out);   // also zeroes out[0]
    vq_main<<<NBLK, 256, 0, stream>>>(z, emb, out);
}

// Round 13
// 150.053 us; speedup vs baseline: 1.4332x; 1.0044x over previous
//
#include <hip/hip_runtime.h>
#include <hip/hip_bf16.h>

// R17: R6 (session-best 61us: codes-mapping, single-pass retention) upgraded:
//  - E-table (64 KB) + en2 staged in LDS ONCE per block, reused 8 tiles ->
//    removes L2 latency from the dense inner loop (R9's attempt poisoned this
//    with per-iter lgkmcnt(0) asm; plain LDS reads pipeline via counted wait).
//  - persistent grid 256 = 1 block/CU (LDS-forced, 91 KB), TPB=8, z register
//    prefetch per tile -> 8x launch/stage amortization.
//  - waves_per_eu(1,1): 512-reg budget; demand ~260 (acc 128 + zf 32 + E
//    in-flight + misc) cannot spill (R7/R8/R15 lesson: spill = demand>budget).
// R16 lesson: barrier-removal is neutral (lockstep refuted); rows-mapping's
// 4x E-stream costs ~13us vs codes-mapping. Codes-mapping + retention (R6)
// minimizes both E-stream and MFMA count.
// Numerics identical to R6/R12 (absmax 0.0): single-product bf16 scores,
// EPS=1e-3 band, exact fp32 reference rescore (same accumulator grouping),
// u64 (dist_bits<<32|idx) atomicMin strict-< ascending-k tie-break.
constexpr int NELEM = 8388608;            // 32*64*64*64
constexpr int ROWS  = 64;                 // rows per tile
constexpr int TPB   = 8;                  // tiles per block
constexpr int NBLK  = 131072 / ROWS / TPB;  // 256 blocks = 1/CU (LDS-forced)
constexpr int ZS    = 68;                 // fp32 z tile stride (dwords)
constexpr float EPS = 1e-3f;              // band (R6-validated)
constexpr int QCAP  = 1024;               // shared candidate queue (~110/tile)

typedef short bf16x8 __attribute__((ext_vector_type(8)));
typedef float v4f    __attribute__((ext_vector_type(4)));

// Precomputed E fragments, hi-only, scale -2: [ct][kc][lane] -> 8 bf16, 64 KB.
__device__ bf16x8 g_efrag[32][2][64];
// Precomputed ||e||^2 in exact reference quad-accumulator order.
__device__ float  g_en2[512];

__device__ inline bf16x8 cvt_hi8(const float* __restrict__ s, float scale) {
    bf16x8 h;
#pragma unroll
    for (int j = 0; j < 8; ++j) {
        __hip_bfloat16 b = __float2bfloat16(scale * s[j]);
        h[j] = (short)__bfloat16_as_ushort(b);
    }
    return h;
}

// 17 blocks: 0..15 build E fragments (256 entries each), 16 builds en2 + out[0]=0.
__global__ void __launch_bounds__(256) vq_prep(const float* __restrict__ emb,
                                               float* __restrict__ out) {
    const int b = blockIdx.x;
    if (b < 16) {
        const int id   = b * 256 + threadIdx.x;   // (ct,kc,lane), 4096 total
        const int lane = id & 63;
        const int kc   = (id >> 6) & 1;
        const int ct   = id >> 7;
        const float* src = emb + (size_t)(ct * 16 + (lane & 15)) * 64
                               + kc * 32 + (lane >> 4) * 8;
        g_efrag[ct][kc][lane] = cvt_hi8(src, -2.0f);
    } else {
#pragma unroll
        for (int c = 0; c < 2; ++c) {
            const int k = threadIdx.x + c * 256;
            const float4* e4 = (const float4*)(emb + (size_t)k * 64);
            float a = 0.f, bq = 0.f, cc = 0.f, d = 0.f;
#pragma unroll
            for (int i = 0; i < 16; ++i) {
                float4 v = e4[i];
                a += v.x * v.x; bq += v.y * v.y; cc += v.z * v.z; d += v.w * v.w;
            }
            g_en2[k] = (a + bq) + (cc + d);
        }
        if (threadIdx.x == 0) out[0] = 0.f;
    }
}

// Block = 256 threads = 4 waves, 1 block/CU. Per tile: 64 rows x 512 codes;
// wave w owns codes [128w,128w+128) for ALL rows. MFMA 16x16x32: A=-2E
// (m=code), B=Z (n=row), C: col=lane&15 (row), row-of-C=quad*4+reg (code)
// [m89 layout, R5-validated]. Single dense pass, fp32 retention acc[4][8].
__global__ __launch_bounds__(256) __attribute__((amdgpu_waves_per_eu(1, 1)))
void vq_main(const float* __restrict__ z,
             const float* __restrict__ emb,
             float* __restrict__ out) {
    __shared__ bf16x8 s_e[32][2][64];         // 64 KB E table (block-resident)
    __shared__ float s_z[ROWS * ZS];          // 17.4 KB fp32 z tile
    __shared__ float s_en2[512];
    __shared__ float s_zn2[ROWS];
    __shared__ unsigned long long s_key[ROWS];
    __shared__ float s_wmin[ROWS][4];         // per-wave row mins
    __shared__ float s_thr[ROWS];             // global row min + EPS
    __shared__ unsigned s_q[QCAP];            // (row<<16)|code
    __shared__ int s_qn;
    __shared__ float s_lpart[4];

    const int tid  = threadIdx.x;
    const int lane = tid & 63;
    const int wid  = __builtin_amdgcn_readfirstlane(tid >> 6);
    const int mcol = lane & 15;
    const int quad = lane >> 4;
    const int row4 = tid >> 2, seg4 = tid & 3;    // stage/zn2/epilogue mapping

    // ---- once per block: stage E (64 KB), en2, tile 0 z, init ----
#pragma unroll
    for (int i = 0; i < 16; ++i) {
        const int idx = tid + 256 * i;            // 4096 bf16x8 entries
        ((bf16x8*)s_e)[idx] = ((const bf16x8*)g_efrag)[idx];
    }
    s_en2[tid]       = g_en2[tid];
    s_en2[tid + 256] = g_en2[tid + 256];
    {
        const float4* gp = (const float4*)(z +
            ((size_t)blockIdx.x * TPB * ROWS + row4) * 64 + seg4 * 16);
#pragma unroll
        for (int i = 0; i < 4; ++i)
            *(float4*)&s_z[row4 * ZS + seg4 * 16 + i * 4] = gp[i];
    }
    if (tid < ROWS) s_key[tid] = ~0ULL;
    if (tid == 0) s_qn = 0;
    __syncthreads();

    float lacc = 0.f;                             // lane0 of each wave

#pragma unroll 1
    for (int t = 0; t < TPB; ++t) {
        const size_t tb = (size_t)(blockIdx.x * TPB + t) * ROWS;

        // ---- prefetch next tile's z into 16 VGPRs ----
        float4 pf0, pf1, pf2, pf3;
        if (t + 1 < TPB) {
            const float4* gp = (const float4*)(z + (tb + ROWS + row4) * 64 + seg4 * 16);
            pf0 = gp[0]; pf1 = gp[1]; pf2 = gp[2]; pf3 = gp[3];
        }

        // ---- exact zn2 per row (reference quad-accumulator order) ----
        {
            const float* zr = &s_z[row4 * ZS];
            float p = 0.f;
#pragma unroll
            for (int i = 0; i < 16; ++i) p += zr[4 * i + seg4] * zr[4 * i + seg4];
            p += __shfl_xor(p, 1, 64);   // a+b | c+d
            p += __shfl_xor(p, 2, 64);   // (a+b)+(c+d)
            if (seg4 == 0) s_zn2[row4] = p;
        }

        // ---- Z fragments (hi only) for all 4 row-groups: 32 VGPRs ----
        bf16x8 zf[4][2];
#pragma unroll
        for (int rg = 0; rg < 4; ++rg) {
            zf[rg][0] = cvt_hi8(&s_z[(rg * 16 + mcol) * ZS +  0 + quad * 8], 1.0f);
            zf[rg][1] = cvt_hi8(&s_z[(rg * 16 + mcol) * ZS + 32 + quad * 8], 1.0f);
        }

        // ---- single dense pass from LDS, fp32 retention (R6 structure) ----
        v4f acc[4][8];
        float lmin[4];
#pragma unroll
        for (int rg = 0; rg < 4; ++rg) lmin[rg] = 3.402823466e38f;
#pragma unroll
        for (int ct = 0; ct < 8; ++ct) {
            const int gct = wid * 8 + ct;
            bf16x8 e0 = s_e[gct][0][lane];        // LDS: ds_read_b128, counted wait
            bf16x8 e1 = s_e[gct][1][lane];
            v4f base = *(const v4f*)&s_en2[gct * 16 + quad * 4];
#pragma unroll
            for (int rg = 0; rg < 4; ++rg) {
                v4f a = base;
                a = __builtin_amdgcn_mfma_f32_16x16x32_bf16(e0, zf[rg][0], a, 0, 0, 0);
                a = __builtin_amdgcn_mfma_f32_16x16x32_bf16(e1, zf[rg][1], a, 0, 0, 0);
                acc[rg][ct] = a;
                lmin[rg] = fminf(lmin[rg], fminf(fminf(a.x, a.y), fminf(a.z, a.w)));
            }
        }

        // ---- per-row min: quads via shfl, waves via LDS ----
#pragma unroll
        for (int rg = 0; rg < 4; ++rg) {
            float m = lmin[rg];
            m = fminf(m, __shfl_xor(m, 16, 64));
            m = fminf(m, __shfl_xor(m, 32, 64));
            if (quad == 0) s_wmin[rg * 16 + mcol][wid] = m;
        }
        __syncthreads();
        if (tid < ROWS)
            s_thr[tid] = fminf(fminf(s_wmin[tid][0], s_wmin[tid][1]),
                               fminf(s_wmin[tid][2], s_wmin[tid][3])) + EPS;
        __syncthreads();

        // ---- band scan over retained scores -> shared queue ----
#pragma unroll
        for (int rg = 0; rg < 4; ++rg) {
            const float thr = s_thr[rg * 16 + mcol];
#pragma unroll
            for (int ct = 0; ct < 8; ++ct) {
                v4f a = acc[rg][ct];
                float m4 = fminf(fminf(a.x, a.y), fminf(a.z, a.w));
                if (m4 <= thr) {
#pragma unroll
                    for (int r = 0; r < 4; ++r) {
                        if (a[r] <= thr) {
                            int slot = atomicAdd(&s_qn, 1);
                            if (slot < QCAP)
                                s_q[slot] = ((unsigned)(rg * 16 + mcol) << 16) |
                                            (unsigned)(wid * 128 + ct * 16 + quad * 4 + r);
                        }
                    }
                }
            }
        }
        __syncthreads();

        // ---- exact reference rescore of candidates (block-parallel) ----
        {
            const int qn = s_qn;
            for (int i = tid; i < qn && i < QCAP; i += 256) {
                const unsigned e = s_q[i];
                const int row = e >> 16, code = e & 0xFFFF;
                const float* zr = &s_z[row * ZS];
                const float* er = emb + (size_t)code * 64;
                float a = 0.f, b = 0.f, c2 = 0.f, d = 0.f;
#pragma unroll
                for (int g = 0; g < 16; ++g) {
                    a  += zr[4*g]   * er[4*g];   b += zr[4*g+1] * er[4*g+1];
                    c2 += zr[4*g+2] * er[4*g+2]; d += zr[4*g+3] * er[4*g+3];
                }
                float dot  = (a + b) + (c2 + d);
                float dist = (s_zn2[row] + s_en2[code]) - 2.0f * dot;  // ref expr
                unsigned long long key =
                    ((unsigned long long)__float_as_uint(dist) << 32) | (unsigned)code;
                atomicMin(&s_key[row], key);
            }
        }
        __syncthreads();

        // ---- epilogue: quantized_st, indices, loss ----
        {
            const int widx = (int)(unsigned)(s_key[row4] & 0x1FFULL);
            const float* er = emb + (size_t)widx * 64 + seg4 * 16;
            const float* zr = &s_z[row4 * ZS + seg4 * 16];
            float* qo = out + 1 + (tb + row4) * 64 + seg4 * 16;
            float lsum = 0.f;
#pragma unroll
            for (int j = 0; j < 16; ++j) {
                float zv = zr[j], ev = er[j];
                float q = zv + (ev - zv);    // reference STE arithmetic
                float df = q - zv; lsum += df * df;
                qo[j] = q;
            }
            if (seg4 == 0)
                out[1 + NELEM + tb + row4] = (float)widx;
#pragma unroll
            for (int off = 32; off; off >>= 1) lsum += __shfl_down(lsum, off, 64);
            if (lane == 0) lacc += lsum;
            if (tid == 0) s_qn = 0;          // safe: rescore done, epilogue ignores
        }

        // ---- turnover: reset keys (wave-local rows), stage next z tile ----
        if (lane < 16) s_key[wid * 16 + lane] = ~0ULL;
        if (t + 1 < TPB) {
            float* d = &s_z[row4 * ZS + seg4 * 16];   // same-thread rows as epilogue
            *(float4*)&d[0]  = pf0;  *(float4*)&d[4]  = pf1;
            *(float4*)&d[8]  = pf2;  *(float4*)&d[12] = pf3;
        }
        __syncthreads();   // next tile's zn2/cvt read all rows
    }

    // ---- one final block reduction for the loss ----
    if (lane == 0) s_lpart[wid] = lacc;
    __syncthreads();
    if (tid == 0) {
        float p = (s_lpart[0] + s_lpart[1]) + (s_lpart[2] + s_lpart[3]);
        atomicAdd(out, p * (1.25f / 8388608.0f));   // recon + 0.25*commit
    }
}

extern "C" void kernel_launch(void* const* d_in, const int* in_sizes, int n_in,
                              void* d_out, int out_size, void* d_ws, size_t ws_size,
                              hipStream_t stream) {
    const float* z   = (const float*)d_in[0];
    const float* emb = (const float*)d_in[1];
    float* out = (float*)d_out;

    vq_prep<<<17, 256, 0, stream>>>(emb, out);   // also zeroes out[0]
    vq_main<<<NBLK, 256, 0, stream>>>(z, emb, out);
}

// Round 14
// 134.861 us; speedup vs baseline: 1.5946x; 1.1126x over previous
//
#include <hip/hip_runtime.h>
#include <hip/hip_bf16.h>

// R18: R12 verbatim with ONE variable changed: waves_per_eu (4,4) -> (6,6).
// R17 lesson closed the occupancy curve: 1 blk/CU=90us, ~2=61-64, ~2.7=64 —
// saturation was never reached because (4,4) capped residency below what LDS
// (25.6 KB -> 6 blocks/CU) allows. (6,6) budget ~340 regs >> demand 52 ->
// zero spill risk (looser ceiling than (4,4), so the R7 squeeze can't recur).
// Mechanism under test: cross-block latency overlap (block A's barrier/LDS
// waits covered by block B's dense loop) — the only lever consistent with
// the R6-R17 invariance record.
// Numerics identical to R6-R13 (absmax 0.0): single-product bf16 scores
// (emb ~ U(+-1/512) -> score err std ~6e-5), EPS=1e-3 band, exact fp32
// reference rescore, u64 (dist_bits<<32|idx) atomicMin strict-< tie-break.
// Both passes use identical zf/e/base bits -> pass1 min == pass2 min exactly.
constexpr int NELEM = 8388608;            // 32*64*64*64
constexpr int ROWS  = 64;                 // rows per block
constexpr int NBLK  = 131072 / ROWS;      // 2048
constexpr int ZS    = 68;                 // fp32 z tile stride (dwords)
constexpr float EPS = 1e-3f;              // single-product band (R6-validated)
constexpr int QCAP  = 1024;               // candidate queue (~110 expected)

typedef short bf16x8 __attribute__((ext_vector_type(8)));
typedef float v4f    __attribute__((ext_vector_type(4)));

// Precomputed E fragments, hi-only, scale -2: [ct][kc][lane] -> 8 bf16, 64 KB.
__device__ bf16x8 g_efrag[32][2][64];
// Precomputed ||e||^2 in exact reference quad-accumulator order.
__device__ float  g_en2[512];

__device__ inline bf16x8 cvt_hi8(const float* __restrict__ s, float scale) {
    bf16x8 h;
#pragma unroll
    for (int j = 0; j < 8; ++j) {
        __hip_bfloat16 b = __float2bfloat16(scale * s[j]);
        h[j] = (short)__bfloat16_as_ushort(b);
    }
    return h;
}

// 17 blocks: 0..15 build E fragments (256 entries each), 16 builds en2 + out[0]=0.
__global__ void __launch_bounds__(256) vq_prep(const float* __restrict__ emb,
                                               float* __restrict__ out) {
    const int b = blockIdx.x;
    if (b < 16) {
        const int id   = b * 256 + threadIdx.x;   // (ct,kc,lane), 4096 total
        const int lane = id & 63;
        const int kc   = (id >> 6) & 1;
        const int ct   = id >> 7;
        const float* src = emb + (size_t)(ct * 16 + (lane & 15)) * 64
                               + kc * 32 + (lane >> 4) * 8;
        g_efrag[ct][kc][lane] = cvt_hi8(src, -2.0f);
    } else {
#pragma unroll
        for (int c = 0; c < 2; ++c) {
            const int k = threadIdx.x + c * 256;
            const float4* e4 = (const float4*)(emb + (size_t)k * 64);
            float a = 0.f, bq = 0.f, cc = 0.f, d = 0.f;
#pragma unroll
            for (int i = 0; i < 16; ++i) {
                float4 v = e4[i];
                a += v.x * v.x; bq += v.y * v.y; cc += v.z * v.z; d += v.w * v.w;
            }
            g_en2[k] = (a + bq) + (cc + d);
        }
        if (threadIdx.x == 0) out[0] = 0.f;
    }
}

// Block = 256 threads = 4 waves, 64 rows x 512 codes. Wave w owns codes
// [128w,128w+128) for ALL 64 rows (reads only its 16 KB E slice per pass).
// MFMA 16x16x32: A=-2E (m=code), B=Z (n=row), C: col=lane&15 (row),
// row-of-C=quad*4+reg (code) [m89 layout, R5-validated].
// Two-pass: pass1 -> per-row min (cross-wave LDS reduce), pass2 recompute +
// band scan. Z fragments zf[4][2] (32 VGPRs) computed once.
__global__ __launch_bounds__(256) __attribute__((amdgpu_waves_per_eu(6, 6)))
void vq_main(const float* __restrict__ z,
             const float* __restrict__ emb,
             float* __restrict__ out) {
    __shared__ float s_z[ROWS * ZS];          // 17.4 KB fp32 z tile
    __shared__ float s_en2[512];
    __shared__ float s_zn2[ROWS];
    __shared__ unsigned long long s_key[ROWS];
    __shared__ float s_wmin[ROWS][4];         // per-wave row mins
    __shared__ float s_thr[ROWS];             // global row min + EPS
    __shared__ unsigned s_q[QCAP];            // (row<<16)|code
    __shared__ int s_qn;
    __shared__ float s_lpart[4];

    const int tid  = threadIdx.x;
    const int lane = tid & 63;
    const int wid  = __builtin_amdgcn_readfirstlane(tid >> 6);
    const int mcol = lane & 15;
    const int quad = lane >> 4;

    // ---- stage z tile (coalesced), load en2, init queue/keys ----
    {
        const int row = tid >> 2, seg = tid & 3;
        const float4* gp = (const float4*)(z + ((size_t)blockIdx.x * ROWS + row) * 64 + seg * 16);
#pragma unroll
        for (int i = 0; i < 4; ++i)
            *(float4*)&s_z[row * ZS + seg * 16 + i * 4] = gp[i];
    }
    s_en2[tid]       = g_en2[tid];
    s_en2[tid + 256] = g_en2[tid + 256];
    if (tid < ROWS) s_key[tid] = ~0ULL;
    if (tid == 0) s_qn = 0;
    __syncthreads();

    // ---- exact zn2 per row, 4-way parallel with reference arithmetic:
    //      accumulator s sums z[4i+s] sequentially; combine (a+b)+(c+d).
    {
        const int row = tid >> 2, s = tid & 3;
        const float* zr = &s_z[row * ZS];
        float p = 0.f;
#pragma unroll
        for (int i = 0; i < 16; ++i) p += zr[4 * i + s] * zr[4 * i + s];
        p += __shfl_xor(p, 1, 64);   // a+b | c+d (fp add commutative: bit-exact)
        p += __shfl_xor(p, 2, 64);   // (a+b)+(c+d)
        if (s == 0) s_zn2[row] = p;
    }

    // ---- Z fragments (hi only) for all 4 row-groups: 32 VGPRs, cvt once ----
    bf16x8 zf[4][2];
#pragma unroll
    for (int rg = 0; rg < 4; ++rg) {
        zf[rg][0] = cvt_hi8(&s_z[(rg * 16 + mcol) * ZS +  0 + quad * 8], 1.0f);
        zf[rg][1] = cvt_hi8(&s_z[(rg * 16 + mcol) * ZS + 32 + quad * 8], 1.0f);
    }

    // ---- pass 1: row mins only (unroll 2: ~32 e-regs in flight) ----
    float lmin[4];
#pragma unroll
    for (int rg = 0; rg < 4; ++rg) lmin[rg] = 3.402823466e38f;
#pragma unroll 2
    for (int ct = 0; ct < 8; ++ct) {
        const int gct = wid * 8 + ct;
        bf16x8 e0 = g_efrag[gct][0][lane];
        bf16x8 e1 = g_efrag[gct][1][lane];
        v4f base = *(const v4f*)&s_en2[gct * 16 + quad * 4];  // broadcast read
#pragma unroll
        for (int rg = 0; rg < 4; ++rg) {
            v4f a = base;
            a = __builtin_amdgcn_mfma_f32_16x16x32_bf16(e0, zf[rg][0], a, 0, 0, 0);
            a = __builtin_amdgcn_mfma_f32_16x16x32_bf16(e1, zf[rg][1], a, 0, 0, 0);
            lmin[rg] = fminf(lmin[rg], fminf(fminf(a.x, a.y), fminf(a.z, a.w)));
        }
    }

    // ---- per-row min: reduce across quads, then across waves via LDS ----
#pragma unroll
    for (int rg = 0; rg < 4; ++rg) {
        float m = lmin[rg];
        m = fminf(m, __shfl_xor(m, 16, 64));
        m = fminf(m, __shfl_xor(m, 32, 64));
        if (quad == 0) s_wmin[rg * 16 + mcol][wid] = m;
    }
    __syncthreads();
    if (tid < ROWS)
        s_thr[tid] = fminf(fminf(s_wmin[tid][0], s_wmin[tid][1]),
                           fminf(s_wmin[tid][2], s_wmin[tid][3])) + EPS;
    __syncthreads();

    // ---- pass 2: recompute (identical bits -> deterministic), band scan ----
    float thr[4];
#pragma unroll
    for (int rg = 0; rg < 4; ++rg) thr[rg] = s_thr[rg * 16 + mcol];
#pragma unroll 2
    for (int ct = 0; ct < 8; ++ct) {
        const int gct = wid * 8 + ct;
        bf16x8 e0 = g_efrag[gct][0][lane];
        bf16x8 e1 = g_efrag[gct][1][lane];
        v4f base = *(const v4f*)&s_en2[gct * 16 + quad * 4];
#pragma unroll
        for (int rg = 0; rg < 4; ++rg) {
            v4f a = base;
            a = __builtin_amdgcn_mfma_f32_16x16x32_bf16(e0, zf[rg][0], a, 0, 0, 0);
            a = __builtin_amdgcn_mfma_f32_16x16x32_bf16(e1, zf[rg][1], a, 0, 0, 0);
            float m4 = fminf(fminf(a.x, a.y), fminf(a.z, a.w));
            if (m4 <= thr[rg]) {
#pragma unroll
                for (int r = 0; r < 4; ++r) {
                    if (a[r] <= thr[rg]) {
                        int slot = atomicAdd(&s_qn, 1);
                        if (slot < QCAP)
                            s_q[slot] = ((unsigned)(rg * 16 + mcol) << 16) |
                                        (unsigned)(wid * 128 + ct * 16 + quad * 4 + r);
                    }
                }
            }
        }
    }
    __syncthreads();

    // ---- exact reference rescore of candidates (parallel pass) ----
    {
        const int qn = s_qn;
        for (int i = tid; i < qn && i < QCAP; i += 256) {
            const unsigned e = s_q[i];
            const int row = e >> 16, code = e & 0xFFFF;
            const float* zr = &s_z[row * ZS];
            const float* er = emb + (size_t)code * 64;
            float a = 0.f, b = 0.f, c2 = 0.f, d = 0.f;
#pragma unroll
            for (int g = 0; g < 16; ++g) {
                a  += zr[4*g]   * er[4*g];   b += zr[4*g+1] * er[4*g+1];
                c2 += zr[4*g+2] * er[4*g+2]; d += zr[4*g+3] * er[4*g+3];
            }
            float dot  = (a + b) + (c2 + d);
            float dist = (s_zn2[row] + s_en2[code]) - 2.0f * dot;  // reference expr
            unsigned long long key =
                ((unsigned long long)__float_as_uint(dist) << 32) | (unsigned)code;
            atomicMin(&s_key[row], key);
        }
    }
    __syncthreads();

    // ---- epilogue: quantized_st, indices, loss (row = tid>>2, 16 floats) ----
    const int row = tid >> 2, seg = tid & 3;
    const int widx = (int)(unsigned)(s_key[row] & 0x1FFULL);
    const float* er = emb + (size_t)widx * 64 + seg * 16;
    const float* zr = &s_z[row * ZS + seg * 16];
    float* qo = out + 1 + ((size_t)blockIdx.x * ROWS + row) * 64 + seg * 16;
    float lsum = 0.f;
#pragma unroll
    for (int j = 0; j < 16; ++j) {
        float zv = zr[j], ev = er[j];
        float q = zv + (ev - zv);    // reference STE arithmetic
        float df = q - zv; lsum += df * df;
        qo[j] = q;
    }
    if (seg == 0)
        out[1 + NELEM + blockIdx.x * ROWS + row] = (float)widx;

#pragma unroll
    for (int off = 32; off; off >>= 1) lsum += __shfl_down(lsum, off, 64);
    if (lane == 0) s_lpart[wid] = lsum;
    __syncthreads();
    if (tid == 0) {
        float p = (s_lpart[0] + s_lpart[1]) + (s_lpart[2] + s_lpart[3]);
        atomicAdd(out, p * (1.25f / 8388608.0f));   // recon + 0.25*commit
    }
}

extern "C" void kernel_launch(void* const* d_in, const int* in_sizes, int n_in,
                              void* d_out, int out_size, void* d_ws, size_t ws_size,
                              hipStream_t stream) {
    const float* z   = (const float*)d_in[0];
    const float* emb = (const float*)d_in[1];
    float* out = (float*)d_out;

    vq_prep<<<17, 256, 0, stream>>>(emb, out);   // also zeroes out[0]
    vq_main<<<NBLK, 256, 0, stream>>>(z, emb, out);
}